// Round 6
// baseline (1799.028 us; speedup 1.0000x reference)
//
#include <hip/hip_runtime.h>

typedef __attribute__((ext_vector_type(4))) float f32x4;
typedef __attribute__((ext_vector_type(8))) short s16x8;
typedef __attribute__((ext_vector_type(4))) short s16x4;

__device__ __forceinline__ short f2bf(float f) {
  union { float f; unsigned u; } v; v.f = f;
  unsigned r = (v.u + 0x7fffu + ((v.u >> 16) & 1u)) >> 16;
  return (short)(r & 0xffffu);
}
__device__ __forceinline__ float bf2f(short s) {
  union { unsigned u; float f; } v; v.u = ((unsigned)(unsigned short)s) << 16;
  return v.f;
}
__device__ __forceinline__ f32x4 mfma16(s16x8 a, s16x8 b, f32x4 c) {
  return __builtin_amdgcn_mfma_f32_16x16x32_bf16(a, b, c, 0, 0, 0);
}

#define AS1(p) ((__attribute__((address_space(1))) void*)(p))
#define AS3(p) ((__attribute__((address_space(3))) void*)(p))

// ---------------- fp32 -> bf16 convert ----------------
__global__ __launch_bounds__(256) void cvt_bf16_kernel(const float* __restrict__ in,
                                                       short* __restrict__ out, long n) {
  long i = ((long)blockIdx.x * 256 + threadIdx.x) * 4;
  if (i + 4 <= n) {
    f32x4 v = *(const f32x4*)(in + i);
    s16x4 o;
    o[0] = f2bf(v[0]); o[1] = f2bf(v[1]); o[2] = f2bf(v[2]); o[3] = f2bf(v[3]);
    *(s16x4*)(out + i) = o;
  }
}

// ---------------- concat 3 bias vectors ----------------
__global__ __launch_bounds__(256) void bias_cat_kernel(const float* __restrict__ bq,
                                                       const float* __restrict__ bk,
                                                       const float* __restrict__ bv,
                                                       float* __restrict__ o) {
  int i = blockIdx.x * 256 + threadIdx.x;
  if (i < 3072) o[i] = (i < 1024) ? bq[i] : ((i < 2048) ? bk[i - 1024] : bv[i - 2048]);
}

// ---------------- rel table prep ----------------
__global__ __launch_bounds__(64) void prep_rel_kernel(
    const float* __restrict__ rq, const float* __restrict__ rk, const float* __restrict__ rv,
    short* __restrict__ relqb, short* __restrict__ relkb, short* __restrict__ relvT,
    float* __restrict__ Dh) {
  int h = blockIdx.x / 240;
  int r = blockIdx.x % 240;
  int d = threadIdx.x;
  float vq = 0.f, vk = 0.f, vv = 0.f;
  if (r < 225) {
    long o = ((long)h * 225 + r) * 64 + d;
    vq = rq[o]; vk = rk[o]; vv = rv[o];
  }
  relqb[((long)h * 240 + r) * 64 + d] = f2bf(vq);
  relkb[((long)h * 240 + r) * 64 + d] = f2bf(vk);
  relvT[((long)h * 64 + d) * 256 + r] = f2bf(vv);
  if (r < 16) relvT[((long)h * 64 + d) * 256 + 240 + r] = 0;
  float p = vq * vk;
  #pragma unroll
  for (int m = 32; m >= 1; m >>= 1) p += __shfl_xor(p, m);
  if (d == 0) Dh[h * 240 + r] = p;
}

// ============ 256x256 8-phase GEMM: C = A(M x K, lda) @ Bw(N x K)^T + bias ============
#define BAR  __builtin_amdgcn_s_barrier()
#define LGK0 do { asm volatile("s_waitcnt lgkmcnt(0)" ::: "memory"); \
                  __builtin_amdgcn_sched_barrier(0); } while (0)
#define VM4  asm volatile("s_waitcnt vmcnt(4)" ::: "memory")
#define VM0  asm volatile("s_waitcnt vmcnt(0)" ::: "memory")
#define PRIO1 __builtin_amdgcn_s_setprio(1)
#define PRIO0 __builtin_amdgcn_s_setprio(0)

#define STG_A(D, H, KOFF) do { \
    const short* _s = gA + (long)(H) * 128 * ldaL + (KOFF); \
    char* _d = lds + (D) * 32768 + (H) * 16384 + ldsw; \
    __builtin_amdgcn_global_load_lds(AS1(_s), AS3(_d), 16, 0, 0); \
    __builtin_amdgcn_global_load_lds(AS1(_s + 64 * ldaL), AS3(_d + 8192), 16, 0, 0); \
  } while (0)
#define STG_B(D, H, KOFF) do { \
    const short* _s = gB + (long)(H) * 128 * ldbL + (KOFF); \
    char* _d = lds + 65536 + (D) * 32768 + (H) * 16384 + ldsw; \
    __builtin_amdgcn_global_load_lds(AS1(_s), AS3(_d), 16, 0, 0); \
    __builtin_amdgcn_global_load_lds(AS1(_s + 64 * ldbL), AS3(_d + 8192), 16, 0, 0); \
  } while (0)
#define RD_A(D, MIH) do { \
    const char* _b = lds + (D) * 32768 + baseA + (MIH) * 8192; \
    _Pragma("unroll") for (int i = 0; i < 4; i++) { \
      aa[0][i] = *(const s16x8*)(_b + i * 2048 + cax0); \
      aa[1][i] = *(const s16x8*)(_b + i * 2048 + cax1); \
    } } while (0)
#define RD_B(D, NJH) do { \
    const char* _b = lds + (D) * 32768 + baseB + (NJH) * 4096; \
    _Pragma("unroll") for (int j = 0; j < 2; j++) { \
      bb[0][(NJH) * 2 + j] = *(const s16x8*)(_b + j * 2048 + cax0); \
      bb[1][(NJH) * 2 + j] = *(const s16x8*)(_b + j * 2048 + cax1); \
    } } while (0)
// swapped operands: fragment reg j indexes consecutive N-cols (C^T layout)
#define MM_Q(MIH, NJH) do { \
    _Pragma("unroll") for (int i = 0; i < 4; i++) { \
      _Pragma("unroll") for (int j = 0; j < 2; j++) { \
        f32x4& c = acc[(MIH) * 4 + i][(NJH) * 2 + j]; \
        c = mfma16(bb[0][(NJH) * 2 + j], aa[0][i], c); \
        c = mfma16(bb[1][(NJH) * 2 + j], aa[1][i], c); \
    } } } while (0)

template<int OUT_BF16>
__global__ __launch_bounds__(512, 2) void gemm256_kernel(
    const short* __restrict__ A, const short* __restrict__ Bw,
    const float* __restrict__ bias, void* __restrict__ Cout,
    int N, int K, int lda) {
  __shared__ __attribute__((aligned(16))) char lds[131072];
  const int tid = threadIdx.x, lane = tid & 63, w = tid >> 6;
  const int wr = w >> 2, wc = w & 3;
  const int l15 = lane & 15, l4 = lane >> 4;
  const int nbn = N >> 8;
  const int nwg = gridDim.x, bid = blockIdx.x;
  const int swz = ((bid & 7) * (nwg >> 3)) + (bid >> 3);   // XCD swizzle (nwg%8==0)
  const int bm = swz / nbn, bn = swz % nbn;

  const int srow = tid >> 3;
  const int scol = ((tid & 7) ^ (srow & 7)) * 8;           // pre-swizzled source chunk
  const long ldaL = lda, ldbL = K;
  const short* gA = A  + ((long)(bm * 256 + srow)) * ldaL + scol;
  const short* gB = Bw + ((long)(bn * 256 + srow)) * ldbL + scol;
  const int ldsw = w * 1024;

  const int baseA = (wr * 128 + l15) * 128;
  const int baseB = 65536 + (wc * 64 + l15) * 128;
  const int cax0 = ((l4) ^ (l15 & 7)) * 16;
  const int cax1 = ((4 + l4) ^ (l15 & 7)) * 16;

  f32x4 acc[8][4];
  #pragma unroll
  for (int i = 0; i < 8; i++)
    #pragma unroll
    for (int j = 0; j < 4; j++) acc[i][j] = (f32x4){0.f, 0.f, 0.f, 0.f};
  s16x8 aa[2][4], bb[2][4];

  // prologue: kt0 fully + B-halves of kt1
  STG_A(0, 0, 0); STG_A(0, 1, 0); STG_B(0, 0, 0); STG_B(0, 1, 0);
  STG_B(1, 0, 64); STG_B(1, 1, 64);
  VM4;
  BAR;

  const int NT = K >> 6;
  for (int kt = 0; kt < NT; kt += 2) {
    const int k1 = (kt + 1) << 6, k2 = (kt + 2) << 6, k3 = (kt + 3) << 6;
    const bool full = (kt + 2) < NT;
    // ---- K-tile kt (buf0) ----
    STG_A(1, 0, k1);
    RD_A(0, 0); RD_B(0, 0);
    BAR; LGK0; PRIO1; MM_Q(0, 0); PRIO0; BAR;
    STG_A(1, 1, k1);
    RD_B(0, 1);
    BAR; LGK0; PRIO1; MM_Q(0, 1); PRIO0; BAR;
    if (full) STG_B(0, 0, k2);
    RD_A(0, 1);
    BAR; LGK0; PRIO1; MM_Q(1, 0); PRIO0; BAR;
    if (full) STG_B(0, 1, k2);
    BAR; LGK0; PRIO1; MM_Q(1, 1); PRIO0;
    if (full) { VM4; } else { VM0; }
    BAR;
    // ---- K-tile kt+1 (buf1) ----
    if (full) STG_A(0, 0, k2);
    RD_A(1, 0); RD_B(1, 0);
    BAR; LGK0; PRIO1; MM_Q(0, 0); PRIO0; BAR;
    if (full) STG_A(0, 1, k2);
    RD_B(1, 1);
    BAR; LGK0; PRIO1; MM_Q(0, 1); PRIO0; BAR;
    if (full) STG_B(1, 0, k3);
    RD_A(1, 1);
    BAR; LGK0; PRIO1; MM_Q(1, 0); PRIO0; BAR;
    if (full) STG_B(1, 1, k3);
    BAR; LGK0; PRIO1; MM_Q(1, 1); PRIO0;
    if (full) { VM4; } else { VM0; }
    BAR;
  }

  // epilogue: C^T fragment layout -> packed nontemporal stores
  const long crow = (long)bm * 256 + wr * 128;
  const int ccol = bn * 256 + wc * 64;
  #pragma unroll
  for (int nj = 0; nj < 4; nj++) {
    const int colb = ccol + nj * 16 + l4 * 4;
    const f32x4 bv4 = *(const f32x4*)&bias[colb];
    #pragma unroll
    for (int mi = 0; mi < 8; mi++) {
      const long row = crow + mi * 16 + l15;
      f32x4 v = acc[mi][nj] + bv4;
      if (OUT_BF16) {
        s16x4 o;
        o[0] = f2bf(v[0]); o[1] = f2bf(v[1]); o[2] = f2bf(v[2]); o[3] = f2bf(v[3]);
        __builtin_nontemporal_store(o, (s16x4*)((short*)Cout + row * N + colb));
      } else {
        __builtin_nontemporal_store(v, (f32x4*)((float*)Cout + row * N + colb));
      }
    }
  }
}

// ---------------- combined qr/kr + gather + v-transpose ----------------
// One block per (b,h). Writes relsum[bh][t][s] = (qr[t,idx]+Dh[idx]+kr[s,idx])*0.125 (bf16)
// and vT[b][h][d][t].  LDS rows are 512 B so the XOR swizzle stays in-row (R5 bug fix).
__global__ __launch_bounds__(256, 2) void qrel_kernel(
    const short* __restrict__ qkv, const short* __restrict__ relqb,
    const short* __restrict__ relkb, const float* __restrict__ Dh,
    const int* __restrict__ rel_index, short* __restrict__ relsum,
    short* __restrict__ vT) {
  __shared__ __attribute__((aligned(16))) char qrs[32768];  // 4 waves x [16][512B] swz
  __shared__ __attribute__((aligned(16))) char krs[32768];  // [64][512B] swz
  __shared__ __attribute__((aligned(16))) short vtb[5120];  // [64][80]

  const int tid = threadIdx.x, lane = tid & 63, w = tid >> 6;
  const int l15 = lane & 15, l4 = lane >> 4;
  const int bh = blockIdx.x, b = bh >> 4, h = bh & 15;
  const f32x4 zero = {0.f, 0.f, 0.f, 0.f};

  // stage v rows (for transpose after barrier)
  {
    const int t = tid >> 2, c0 = (tid & 3) * 16;
    const long g = ((long)(b * 64 + t)) * 3072 + 2048 + h * 64 + c0;
    *(s16x8*)&vtb[t * 80 + c0] = *(const s16x8*)(qkv + g);
    *(s16x8*)&vtb[t * 80 + c0 + 8] = *(const s16x8*)(qkv + g + 8);
  }

  // q,k fragments (rows w*16+l15)
  const long qbase = ((long)(b * 64 + w * 16 + l15)) * 3072 + h * 64;
  s16x8 aq0 = *(const s16x8*)(qkv + qbase + l4 * 8);
  s16x8 aq1 = *(const s16x8*)(qkv + qbase + 32 + l4 * 8);
  s16x8 ak0 = *(const s16x8*)(qkv + qbase + 1024 + l4 * 8);
  s16x8 ak1 = *(const s16x8*)(qkv + qbase + 1056 + l4 * 8);

  const short* rkh = relkb + (long)h * 240 * 64;
  const short* rqh = relqb + (long)h * 240 * 64;
  char* qw = qrs + w * 8192;
  #pragma unroll
  for (int nj = 0; nj < 15; nj++) {
    const int rr = nj * 16 + l15;
    s16x8 b0 = *(const s16x8*)(rkh + rr * 64 + l4 * 8);
    s16x8 b1 = *(const s16x8*)(rkh + rr * 64 + 32 + l4 * 8);
    f32x4 t0 = mfma16(aq1, b1, mfma16(aq0, b0, zero));
    s16x8 c0v = *(const s16x8*)(rqh + rr * 64 + l4 * 8);
    s16x8 c1v = *(const s16x8*)(rqh + rr * 64 + 32 + l4 * 8);
    f32x4 t1 = mfma16(ak1, c1v, mfma16(ak0, c0v, zero));
    const float dv = Dh[h * 240 + rr];
    #pragma unroll
    for (int j = 0; j < 4; j++) {
      const int rloc = l4 * 4 + j;
      *(short*)(qw + rloc * 512 + ((rr * 2) ^ ((rloc & 7) << 4))) = f2bf(t0[j] + dv);
      const int srow = w * 16 + rloc;
      *(short*)(krs + srow * 512 + ((rr * 2) ^ ((srow & 7) << 4))) = f2bf(t1[j]);
    }
  }
  __syncthreads();

  // gather + sum + scale -> relsum (wave-own t rows)
  short* rsb = relsum + (long)bh * 4096;
  #pragma unroll
  for (int n = 0; n < 4; n++)
    #pragma unroll
    for (int j = 0; j < 4; j++) {
      const int tl = l4 * 4 + j;
      const int t = w * 16 + tl, s = n * 16 + l15;
      const int r = rel_index[t * 64 + s];
      float qg = bf2f(*(const short*)(qw + tl * 512 + ((r * 2) ^ ((tl & 7) << 4))));
      float kg = bf2f(*(const short*)(krs + s * 512 + ((r * 2) ^ ((s & 7) << 4))));
      rsb[t * 64 + s] = f2bf((qg + kg) * 0.125f);
    }

  // vT write
  {
    const int d = tid >> 2, t0c = (tid & 3) * 16;
    short* o = vT + ((long)(b * 16 + h)) * 4096 + d * 64 + t0c;
    s16x8 v0, v1;
    #pragma unroll
    for (int i = 0; i < 8; i++) {
      v0[i] = vtb[(t0c + i) * 80 + d];
      v1[i] = vtb[(t0c + 8 + i) * 80 + d];
    }
    *(s16x8*)o = v0;
    *(s16x8*)(o + 8) = v1;
  }
}

// ---------------- barrier-free fused attention ----------------
__global__ __launch_bounds__(256, 4) void attn_kernel(
    const short* __restrict__ qkv, const short* __restrict__ relsum,
    const short* __restrict__ relvT, const short* __restrict__ vT,
    const int* __restrict__ rel_index, short* __restrict__ aout) {
  __shared__ __attribute__((aligned(16))) char Pb[40960];

  const int tid = threadIdx.x, lane = tid & 63, w = tid >> 6;
  const int l15 = lane & 15, l4 = lane >> 4;
  const int bh = blockIdx.x, b = bh >> 4, h = bh & 15;
  const f32x4 zero = {0.f, 0.f, 0.f, 0.f};

  const long qbase = ((long)(b * 64 + w * 16 + l15)) * 3072 + h * 64;
  s16x8 aq0 = *(const s16x8*)(qkv + qbase + l4 * 8);
  s16x8 aq1 = *(const s16x8*)(qkv + qbase + 32 + l4 * 8);

  f32x4 sacc[4];
  sacc[0] = sacc[1] = sacc[2] = sacc[3] = zero;
  #pragma unroll
  for (int n = 0; n < 4; n++) {
    const long kb = ((long)(b * 64 + n * 16 + l15)) * 3072 + 1024 + h * 64;
    s16x8 b0 = *(const s16x8*)(qkv + kb + l4 * 8);
    s16x8 b1 = *(const s16x8*)(qkv + kb + 32 + l4 * 8);
    sacc[n] = mfma16(aq0, b0, sacc[n]);
    sacc[n] = mfma16(aq1, b1, sacc[n]);
  }

  // add precomputed relative term (coalesced), softmax
  const short* rsb = relsum + (long)bh * 4096;
  #pragma unroll
  for (int n = 0; n < 4; n++)
    #pragma unroll
    for (int j = 0; j < 4; j++) {
      const int t = w * 16 + l4 * 4 + j, s = n * 16 + l15;
      sacc[n][j] = fmaf(sacc[n][j], 0.125f, bf2f(rsb[t * 64 + s]));
    }
  #pragma unroll
  for (int j = 0; j < 4; j++) {
    float m = fmaxf(fmaxf(sacc[0][j], sacc[1][j]), fmaxf(sacc[2][j], sacc[3][j]));
    m = fmaxf(m, __shfl_xor(m, 1));
    m = fmaxf(m, __shfl_xor(m, 2));
    m = fmaxf(m, __shfl_xor(m, 4));
    m = fmaxf(m, __shfl_xor(m, 8));
    float sum = 0.f;
    #pragma unroll
    for (int n = 0; n < 4; n++) { sacc[n][j] = __expf(sacc[n][j] - m); sum += sacc[n][j]; }
    sum += __shfl_xor(sum, 1);
    sum += __shfl_xor(sum, 2);
    sum += __shfl_xor(sum, 4);
    sum += __shfl_xor(sum, 8);
    const float inv = 1.f / sum;
    #pragma unroll
    for (int n = 0; n < 4; n++) sacc[n][j] *= inv;
  }

  // zero wave-own P region, scatter P + stage attn (swizzled)
  {
    s16x8 z = {0, 0, 0, 0, 0, 0, 0, 0};
    #pragma unroll
    for (int i = 0; i < 8; i++) {
      const int c = lane + 64 * i;
      *(s16x8*)(Pb + (w * 16 + (c >> 5)) * 640 + (c & 31) * 16) = z;
    }
  }
  #pragma unroll
  for (int n = 0; n < 4; n++)
    #pragma unroll
    for (int j = 0; j < 4; j++) {
      const int t = w * 16 + l4 * 4 + j, s = n * 16 + l15;
      const int r = rel_index[t * 64 + s];
      const int sw = (t & 7) << 4;
      const short a = f2bf(sacc[n][j]);
      *(short*)(Pb + t * 640 + ((r * 2) ^ sw)) = a;
      *(short*)(Pb + t * 640 + 512 + ((s * 2) ^ sw)) = a;
    }

  // out^T = [relv^T ; v^T] x [P | attn]^T  (swapped operands: reg j = consecutive d)
  f32x4 oacc[4];
  oacc[0] = oacc[1] = oacc[2] = oacc[3] = zero;
  const int rowp = w * 16 + l15, px = (rowp & 7) << 4;
  const short* rvh = relvT + (long)h * 16384;
  const short* vTb = vT + ((long)(b * 16 + h)) * 4096;
  #pragma unroll
  for (int kk = 0; kk < 8; kk++) {
    s16x8 pa = *(const s16x8*)(Pb + rowp * 640 + ((kk * 64 + l4 * 16) ^ px));
    #pragma unroll
    for (int m = 0; m < 4; m++) {
      s16x8 bbv = *(const s16x8*)(rvh + (m * 16 + l15) * 256 + kk * 32 + l4 * 8);
      oacc[m] = mfma16(bbv, pa, oacc[m]);
    }
  }
  #pragma unroll
  for (int ks = 0; ks < 2; ks++) {
    s16x8 pa = *(const s16x8*)(Pb + rowp * 640 + 512 + ((ks * 64 + l4 * 16) ^ px));
    #pragma unroll
    for (int m = 0; m < 4; m++) {
      s16x8 bbv = *(const s16x8*)(vTb + (m * 16 + l15) * 64 + ks * 32 + l4 * 8);
      oacc[m] = mfma16(bbv, pa, oacc[m]);
    }
  }
  // oacc[m]: out[d = m*16 + l4*4 + j][t = w*16 + l15] -> packed 8-B nt stores
  const long obase = ((long)(b * 64 + w * 16 + l15)) * 1024 + h * 64;
  #pragma unroll
  for (int m = 0; m < 4; m++) {
    s16x4 o;
    o[0] = f2bf(oacc[m][0]); o[1] = f2bf(oacc[m][1]);
    o[2] = f2bf(oacc[m][2]); o[3] = f2bf(oacc[m][3]);
    __builtin_nontemporal_store(o, (s16x4*)(aout + obase + m * 16 + l4 * 4));
  }
}

extern "C" void kernel_launch(void* const* d_in, const int* in_sizes, int n_in,
                              void* d_out, int out_size, void* d_ws, size_t ws_size,
                              hipStream_t stream) {
  const float* x     = (const float*)d_in[0];
  const float* Wq_w  = (const float*)d_in[1];
  const float* Wq_b  = (const float*)d_in[2];
  const float* Wk_w  = (const float*)d_in[3];
  const float* Wk_b  = (const float*)d_in[4];
  const float* Wv_w  = (const float*)d_in[5];
  const float* Wv_b  = (const float*)d_in[6];
  const float* Wo_w  = (const float*)d_in[7];
  const float* Wo_b  = (const float*)d_in[8];
  const float* rel_q = (const float*)d_in[9];
  const float* rel_k = (const float*)d_in[10];
  const float* rel_v = (const float*)d_in[11];
  const int* rel_index = (const int*)d_in[12];
  float* out = (float*)d_out;

  char* ws = (char*)d_ws;
  short* x_bf   = (short*)(ws);                   // 134,217,728 (reused as aout)
  short* qkv_bf = (short*)(ws + 134217728L);      // 402,653,184
  short* wq_bf  = (short*)(ws + 536870912L);      // wq|wk|wv contiguous
  short* wo_bf  = (short*)(ws + 543162368L);
  float* biascat= (float*)(ws + 545259520L);
  short* relqb  = (short*)(ws + 545271808L);
  short* relkb  = (short*)(ws + 545763328L);
  short* relvT  = (short*)(ws + 546254848L);
  float* Dh     = (float*)(ws + 546779136L);
  short* relsum = (short*)(ws + 546794496L);      // 134,217,728
  short* vT     = (short*)(ws + 681012224L);      // 134,217,728
  short* aout   = x_bf;

  cvt_bf16_kernel<<<65536, 256, 0, stream>>>(x, x_bf, 67108864L);
  cvt_bf16_kernel<<<1024, 256, 0, stream>>>(Wq_w, wq_bf, 1048576L);
  cvt_bf16_kernel<<<1024, 256, 0, stream>>>(Wk_w, (short*)(ws + 538968064L), 1048576L);
  cvt_bf16_kernel<<<1024, 256, 0, stream>>>(Wv_w, (short*)(ws + 541065216L), 1048576L);
  cvt_bf16_kernel<<<1024, 256, 0, stream>>>(Wo_w, wo_bf, 1048576L);
  bias_cat_kernel<<<12, 256, 0, stream>>>(Wq_b, Wk_b, Wv_b, biascat);
  prep_rel_kernel<<<3840, 64, 0, stream>>>(rel_q, rel_k, rel_v, relqb, relkb, relvT, Dh);

  gemm256_kernel<1><<<3072, 512, 0, stream>>>(x_bf, wq_bf, biascat, (void*)qkv_bf,
                                              3072, 1024, 1024);
  qrel_kernel<<<16384, 256, 0, stream>>>(qkv_bf, relqb, relkb, Dh, rel_index,
                                         relsum, vT);
  attn_kernel<<<16384, 256, 0, stream>>>(qkv_bf, relsum, relvT, vT, rel_index, aout);
  gemm256_kernel<0><<<1024, 512, 0, stream>>>(aout, wo_bf, Wo_b, (void*)out,
                                              1024, 1024, 1024);
}

// Round 8
// 1681.587 us; speedup vs baseline: 1.0698x; 1.0698x over previous
//
#include <hip/hip_runtime.h>

typedef __attribute__((ext_vector_type(4))) float f32x4;
typedef __attribute__((ext_vector_type(8))) short s16x8;
typedef __attribute__((ext_vector_type(4))) short s16x4;

__device__ __forceinline__ short f2bf(float f) {
  union { float f; unsigned u; } v; v.f = f;
  unsigned r = (v.u + 0x7fffu + ((v.u >> 16) & 1u)) >> 16;
  return (short)(r & 0xffffu);
}
__device__ __forceinline__ float bf2f(short s) {
  union { unsigned u; float f; } v; v.u = ((unsigned)(unsigned short)s) << 16;
  return v.f;
}
__device__ __forceinline__ f32x4 mfma16(s16x8 a, s16x8 b, f32x4 c) {
  return __builtin_amdgcn_mfma_f32_16x16x32_bf16(a, b, c, 0, 0, 0);
}

#define AS1(p) ((__attribute__((address_space(1))) void*)(p))
#define AS3(p) ((__attribute__((address_space(3))) void*)(p))

// ---------------- fp32 -> bf16 convert ----------------
__global__ __launch_bounds__(256) void cvt_bf16_kernel(const float* __restrict__ in,
                                                       short* __restrict__ out, long n) {
  long i = ((long)blockIdx.x * 256 + threadIdx.x) * 4;
  if (i + 4 <= n) {
    f32x4 v = *(const f32x4*)(in + i);
    s16x4 o;
    o[0] = f2bf(v[0]); o[1] = f2bf(v[1]); o[2] = f2bf(v[2]); o[3] = f2bf(v[3]);
    *(s16x4*)(out + i) = o;
  }
}

// ---------------- concat 3 bias vectors ----------------
__global__ __launch_bounds__(256) void bias_cat_kernel(const float* __restrict__ bq,
                                                       const float* __restrict__ bk,
                                                       const float* __restrict__ bv,
                                                       float* __restrict__ o) {
  int i = blockIdx.x * 256 + threadIdx.x;
  if (i < 3072) o[i] = (i < 1024) ? bq[i] : ((i < 2048) ? bk[i - 1024] : bv[i - 2048]);
}

// ---------------- rel table prep ----------------
__global__ __launch_bounds__(64) void prep_rel_kernel(
    const float* __restrict__ rq, const float* __restrict__ rk, const float* __restrict__ rv,
    short* __restrict__ relqb, short* __restrict__ relkb, short* __restrict__ relvT,
    float* __restrict__ Dh) {
  int h = blockIdx.x / 240;
  int r = blockIdx.x % 240;
  int d = threadIdx.x;
  float vq = 0.f, vk = 0.f, vv = 0.f;
  if (r < 225) {
    long o = ((long)h * 225 + r) * 64 + d;
    vq = rq[o]; vk = rk[o]; vv = rv[o];
  }
  relqb[((long)h * 240 + r) * 64 + d] = f2bf(vq);
  relkb[((long)h * 240 + r) * 64 + d] = f2bf(vk);
  relvT[((long)h * 64 + d) * 256 + r] = f2bf(vv);
  if (r < 16) relvT[((long)h * 64 + d) * 256 + 240 + r] = 0;
  float p = vq * vk;
  #pragma unroll
  for (int m = 32; m >= 1; m >>= 1) p += __shfl_xor(p, m);
  if (d == 0) Dh[h * 240 + r] = p;
}

// ============ 256x256 8-phase GEMM: C = A(M x K, lda) @ Bw(N x K)^T + bias ============
// R8 hardening: vmcnt(0) (not counted vmcnt(4)) at the prologue and both per-K-tile
// handoffs — removes any reliance on in-order counted retirement of global_load_lds.
// The 8-phase issue stagger is kept, so staging still overlaps MFMA by 2-4 phases.
#define BAR  __builtin_amdgcn_s_barrier()
#define LGK0 do { asm volatile("s_waitcnt lgkmcnt(0)" ::: "memory"); \
                  __builtin_amdgcn_sched_barrier(0); } while (0)
#define VM0  asm volatile("s_waitcnt vmcnt(0)" ::: "memory")
#define PRIO1 __builtin_amdgcn_s_setprio(1)
#define PRIO0 __builtin_amdgcn_s_setprio(0)

#define STG_A(D, H, KOFF) do { \
    const short* _s = gA + (long)(H) * 128 * ldaL + (KOFF); \
    char* _d = lds + (D) * 32768 + (H) * 16384 + ldsw; \
    __builtin_amdgcn_global_load_lds(AS1(_s), AS3(_d), 16, 0, 0); \
    __builtin_amdgcn_global_load_lds(AS1(_s + 64 * ldaL), AS3(_d + 8192), 16, 0, 0); \
  } while (0)
#define STG_B(D, H, KOFF) do { \
    const short* _s = gB + (long)(H) * 128 * ldbL + (KOFF); \
    char* _d = lds + 65536 + (D) * 32768 + (H) * 16384 + ldsw; \
    __builtin_amdgcn_global_load_lds(AS1(_s), AS3(_d), 16, 0, 0); \
    __builtin_amdgcn_global_load_lds(AS1(_s + 64 * ldbL), AS3(_d + 8192), 16, 0, 0); \
  } while (0)
#define RD_A(D, MIH) do { \
    const char* _b = lds + (D) * 32768 + baseA + (MIH) * 8192; \
    _Pragma("unroll") for (int i = 0; i < 4; i++) { \
      aa[0][i] = *(const s16x8*)(_b + i * 2048 + cax0); \
      aa[1][i] = *(const s16x8*)(_b + i * 2048 + cax1); \
    } } while (0)
#define RD_B(D, NJH) do { \
    const char* _b = lds + (D) * 32768 + baseB + (NJH) * 4096; \
    _Pragma("unroll") for (int j = 0; j < 2; j++) { \
      bb[0][(NJH) * 2 + j] = *(const s16x8*)(_b + j * 2048 + cax0); \
      bb[1][(NJH) * 2 + j] = *(const s16x8*)(_b + j * 2048 + cax1); \
    } } while (0)
// swapped operands: fragment reg j indexes consecutive N-cols (C^T layout)
#define MM_Q(MIH, NJH) do { \
    _Pragma("unroll") for (int i = 0; i < 4; i++) { \
      _Pragma("unroll") for (int j = 0; j < 2; j++) { \
        f32x4& c = acc[(MIH) * 4 + i][(NJH) * 2 + j]; \
        c = mfma16(bb[0][(NJH) * 2 + j], aa[0][i], c); \
        c = mfma16(bb[1][(NJH) * 2 + j], aa[1][i], c); \
    } } } while (0)

template<int OUT_BF16>
__global__ __launch_bounds__(512, 2) void gemm256_kernel(
    const short* __restrict__ A, const short* __restrict__ Bw,
    const float* __restrict__ bias, void* __restrict__ Cout,
    int N, int K, int lda) {
  __shared__ __attribute__((aligned(16))) char lds[131072];
  const int tid = threadIdx.x, lane = tid & 63, w = tid >> 6;
  const int wr = w >> 2, wc = w & 3;
  const int l15 = lane & 15, l4 = lane >> 4;
  const int nbn = N >> 8;
  const int nwg = gridDim.x, bid = blockIdx.x;
  const int swz = ((bid & 7) * (nwg >> 3)) + (bid >> 3);   // XCD swizzle (nwg%8==0)
  const int bm = swz / nbn, bn = swz % nbn;

  const int srow = tid >> 3;
  const int scol = ((tid & 7) ^ (srow & 7)) * 8;           // pre-swizzled source chunk
  const long ldaL = lda, ldbL = K;
  const short* gA = A  + ((long)(bm * 256 + srow)) * ldaL + scol;
  const short* gB = Bw + ((long)(bn * 256 + srow)) * ldbL + scol;
  const int ldsw = w * 1024;

  const int baseA = (wr * 128 + l15) * 128;
  const int baseB = 65536 + (wc * 64 + l15) * 128;
  const int cax0 = ((l4) ^ (l15 & 7)) * 16;
  const int cax1 = ((4 + l4) ^ (l15 & 7)) * 16;

  f32x4 acc[8][4];
  #pragma unroll
  for (int i = 0; i < 8; i++)
    #pragma unroll
    for (int j = 0; j < 4; j++) acc[i][j] = (f32x4){0.f, 0.f, 0.f, 0.f};
  s16x8 aa[2][4], bb[2][4];

  // prologue: kt0 fully + B-halves of kt1; full drain before first compute
  STG_A(0, 0, 0); STG_A(0, 1, 0); STG_B(0, 0, 0); STG_B(0, 1, 0);
  STG_B(1, 0, 64); STG_B(1, 1, 64);
  VM0;
  BAR;

  const int NT = K >> 6;
  for (int kt = 0; kt < NT; kt += 2) {
    const int k1 = (kt + 1) << 6, k2 = (kt + 2) << 6, k3 = (kt + 3) << 6;
    const bool full = (kt + 2) < NT;
    // ---- K-tile kt (buf0) ----
    STG_A(1, 0, k1);
    RD_A(0, 0); RD_B(0, 0);
    BAR; LGK0; PRIO1; MM_Q(0, 0); PRIO0; BAR;
    STG_A(1, 1, k1);
    RD_B(0, 1);
    BAR; LGK0; PRIO1; MM_Q(0, 1); PRIO0; BAR;
    if (full) STG_B(0, 0, k2);
    RD_A(0, 1);
    BAR; LGK0; PRIO1; MM_Q(1, 0); PRIO0; BAR;
    if (full) STG_B(0, 1, k2);
    BAR; LGK0; PRIO1; MM_Q(1, 1); PRIO0;
    VM0;                                          // buf1 (kt+1) fully committed
    BAR;
    // ---- K-tile kt+1 (buf1) ----
    if (full) STG_A(0, 0, k2);
    RD_A(1, 0); RD_B(1, 0);
    BAR; LGK0; PRIO1; MM_Q(0, 0); PRIO0; BAR;
    if (full) STG_A(0, 1, k2);
    RD_B(1, 1);
    BAR; LGK0; PRIO1; MM_Q(0, 1); PRIO0; BAR;
    if (full) STG_B(1, 0, k3);
    RD_A(1, 1);
    BAR; LGK0; PRIO1; MM_Q(1, 0); PRIO0; BAR;
    if (full) STG_B(1, 1, k3);
    BAR; LGK0; PRIO1; MM_Q(1, 1); PRIO0;
    VM0;                                          // buf0 (kt+2) fully committed
    BAR;
  }

  // epilogue: C^T fragment layout -> packed cached stores
  const long crow = (long)bm * 256 + wr * 128;
  const int ccol = bn * 256 + wc * 64;
  #pragma unroll
  for (int nj = 0; nj < 4; nj++) {
    const int colb = ccol + nj * 16 + l4 * 4;
    const f32x4 bv4 = *(const f32x4*)&bias[colb];
    #pragma unroll
    for (int mi = 0; mi < 8; mi++) {
      const long row = crow + mi * 16 + l15;
      f32x4 v = acc[mi][nj] + bv4;
      if (OUT_BF16) {
        s16x4 o;
        o[0] = f2bf(v[0]); o[1] = f2bf(v[1]); o[2] = f2bf(v[2]); o[3] = f2bf(v[3]);
        *(s16x4*)((short*)Cout + row * N + colb) = o;
      } else {
        *(f32x4*)((float*)Cout + row * N + colb) = v;
      }
    }
  }
}

// ---------------- combined qr/kr + gather + v-transpose ----------------
// One block per (b,h). Writes relsum[bh][t][s] = (qr[t,idx]+Dh[idx]+kr[s,idx])*0.125 (bf16)
// and vT[b][h][d][t].  LDS rows are 512 B so the XOR swizzle stays in-row.
__global__ __launch_bounds__(256, 2) void qrel_kernel(
    const short* __restrict__ qkv, const short* __restrict__ relqb,
    const short* __restrict__ relkb, const float* __restrict__ Dh,
    const int* __restrict__ rel_index, short* __restrict__ relsum,
    short* __restrict__ vT) {
  __shared__ __attribute__((aligned(16))) char qrs[32768];  // 4 waves x [16][512B] swz
  __shared__ __attribute__((aligned(16))) char krs[32768];  // [64][512B] swz
  __shared__ __attribute__((aligned(16))) short vtb[5120];  // [64][80]

  const int tid = threadIdx.x, lane = tid & 63, w = tid >> 6;
  const int l15 = lane & 15, l4 = lane >> 4;
  const int bh = blockIdx.x, b = bh >> 4, h = bh & 15;
  const f32x4 zero = {0.f, 0.f, 0.f, 0.f};

  // stage v rows (for transpose after barrier)
  {
    const int t = tid >> 2, c0 = (tid & 3) * 16;
    const long g = ((long)(b * 64 + t)) * 3072 + 2048 + h * 64 + c0;
    *(s16x8*)&vtb[t * 80 + c0] = *(const s16x8*)(qkv + g);
    *(s16x8*)&vtb[t * 80 + c0 + 8] = *(const s16x8*)(qkv + g + 8);
  }

  // q,k fragments (rows w*16+l15)
  const long qbase = ((long)(b * 64 + w * 16 + l15)) * 3072 + h * 64;
  s16x8 aq0 = *(const s16x8*)(qkv + qbase + l4 * 8);
  s16x8 aq1 = *(const s16x8*)(qkv + qbase + 32 + l4 * 8);
  s16x8 ak0 = *(const s16x8*)(qkv + qbase + 1024 + l4 * 8);
  s16x8 ak1 = *(const s16x8*)(qkv + qbase + 1056 + l4 * 8);

  const short* rkh = relkb + (long)h * 240 * 64;
  const short* rqh = relqb + (long)h * 240 * 64;
  char* qw = qrs + w * 8192;
  #pragma unroll
  for (int nj = 0; nj < 15; nj++) {
    const int rr = nj * 16 + l15;
    s16x8 b0 = *(const s16x8*)(rkh + rr * 64 + l4 * 8);
    s16x8 b1 = *(const s16x8*)(rkh + rr * 64 + 32 + l4 * 8);
    f32x4 t0 = mfma16(aq1, b1, mfma16(aq0, b0, zero));
    s16x8 c0v = *(const s16x8*)(rqh + rr * 64 + l4 * 8);
    s16x8 c1v = *(const s16x8*)(rqh + rr * 64 + 32 + l4 * 8);
    f32x4 t1 = mfma16(ak1, c1v, mfma16(ak0, c0v, zero));
    const float dv = Dh[h * 240 + rr];
    #pragma unroll
    for (int j = 0; j < 4; j++) {
      const int rloc = l4 * 4 + j;
      *(short*)(qw + rloc * 512 + ((rr * 2) ^ ((rloc & 7) << 4))) = f2bf(t0[j] + dv);
      const int srow = w * 16 + rloc;
      *(short*)(krs + srow * 512 + ((rr * 2) ^ ((srow & 7) << 4))) = f2bf(t1[j]);
    }
  }
  __syncthreads();

  // gather + sum + scale -> relsum (wave-own t rows)
  short* rsb = relsum + (long)bh * 4096;
  #pragma unroll
  for (int n = 0; n < 4; n++)
    #pragma unroll
    for (int j = 0; j < 4; j++) {
      const int tl = l4 * 4 + j;
      const int t = w * 16 + tl, s = n * 16 + l15;
      const int r = rel_index[t * 64 + s];
      float qg = bf2f(*(const short*)(qw + tl * 512 + ((r * 2) ^ ((tl & 7) << 4))));
      float kg = bf2f(*(const short*)(krs + s * 512 + ((r * 2) ^ ((s & 7) << 4))));
      rsb[t * 64 + s] = f2bf((qg + kg) * 0.125f);
    }

  // vT write
  {
    const int d = tid >> 2, t0c = (tid & 3) * 16;
    short* o = vT + ((long)(b * 16 + h)) * 4096 + d * 64 + t0c;
    s16x8 v0, v1;
    #pragma unroll
    for (int i = 0; i < 8; i++) {
      v0[i] = vtb[(t0c + i) * 80 + d];
      v1[i] = vtb[(t0c + 8 + i) * 80 + d];
    }
    *(s16x8*)o = v0;
    *(s16x8*)(o + 8) = v1;
  }
}

// ---------------- barrier-free fused attention ----------------
__global__ __launch_bounds__(256, 4) void attn_kernel(
    const short* __restrict__ qkv, const short* __restrict__ relsum,
    const short* __restrict__ relvT, const short* __restrict__ vT,
    const int* __restrict__ rel_index, short* __restrict__ aout) {
  __shared__ __attribute__((aligned(16))) char Pb[40960];

  const int tid = threadIdx.x, lane = tid & 63, w = tid >> 6;
  const int l15 = lane & 15, l4 = lane >> 4;
  const int bh = blockIdx.x, b = bh >> 4, h = bh & 15;
  const f32x4 zero = {0.f, 0.f, 0.f, 0.f};

  const long qbase = ((long)(b * 64 + w * 16 + l15)) * 3072 + h * 64;
  s16x8 aq0 = *(const s16x8*)(qkv + qbase + l4 * 8);
  s16x8 aq1 = *(const s16x8*)(qkv + qbase + 32 + l4 * 8);

  f32x4 sacc[4];
  sacc[0] = sacc[1] = sacc[2] = sacc[3] = zero;
  #pragma unroll
  for (int n = 0; n < 4; n++) {
    const long kb = ((long)(b * 64 + n * 16 + l15)) * 3072 + 1024 + h * 64;
    s16x8 b0 = *(const s16x8*)(qkv + kb + l4 * 8);
    s16x8 b1 = *(const s16x8*)(qkv + kb + 32 + l4 * 8);
    sacc[n] = mfma16(aq0, b0, sacc[n]);
    sacc[n] = mfma16(aq1, b1, sacc[n]);
  }

  // add precomputed relative term (coalesced), softmax
  const short* rsb = relsum + (long)bh * 4096;
  #pragma unroll
  for (int n = 0; n < 4; n++)
    #pragma unroll
    for (int j = 0; j < 4; j++) {
      const int t = w * 16 + l4 * 4 + j, s = n * 16 + l15;
      sacc[n][j] = fmaf(sacc[n][j], 0.125f, bf2f(rsb[t * 64 + s]));
    }
  #pragma unroll
  for (int j = 0; j < 4; j++) {
    float m = fmaxf(fmaxf(sacc[0][j], sacc[1][j]), fmaxf(sacc[2][j], sacc[3][j]));
    m = fmaxf(m, __shfl_xor(m, 1));
    m = fmaxf(m, __shfl_xor(m, 2));
    m = fmaxf(m, __shfl_xor(m, 4));
    m = fmaxf(m, __shfl_xor(m, 8));
    float sum = 0.f;
    #pragma unroll
    for (int n = 0; n < 4; n++) { sacc[n][j] = __expf(sacc[n][j] - m); sum += sacc[n][j]; }
    sum += __shfl_xor(sum, 1);
    sum += __shfl_xor(sum, 2);
    sum += __shfl_xor(sum, 4);
    sum += __shfl_xor(sum, 8);
    const float inv = 1.f / sum;
    #pragma unroll
    for (int n = 0; n < 4; n++) sacc[n][j] *= inv;
  }

  // zero wave-own P region, scatter P + stage attn (swizzled)
  {
    s16x8 z = {0, 0, 0, 0, 0, 0, 0, 0};
    #pragma unroll
    for (int i = 0; i < 8; i++) {
      const int c = lane + 64 * i;
      *(s16x8*)(Pb + (w * 16 + (c >> 5)) * 640 + (c & 31) * 16) = z;
    }
  }
  #pragma unroll
  for (int n = 0; n < 4; n++)
    #pragma unroll
    for (int j = 0; j < 4; j++) {
      const int t = w * 16 + l4 * 4 + j, s = n * 16 + l15;
      const int r = rel_index[t * 64 + s];
      const int sw = (t & 7) << 4;
      const short a = f2bf(sacc[n][j]);
      *(short*)(Pb + t * 640 + ((r * 2) ^ sw)) = a;
      *(short*)(Pb + t * 640 + 512 + ((s * 2) ^ sw)) = a;
    }

  // out^T = [relv^T ; v^T] x [P | attn]^T  (swapped operands: reg j = consecutive d)
  f32x4 oacc[4];
  oacc[0] = oacc[1] = oacc[2] = oacc[3] = zero;
  const int rowp = w * 16 + l15, px = (rowp & 7) << 4;
  const short* rvh = relvT + (long)h * 16384;
  const short* vTb = vT + ((long)(b * 16 + h)) * 4096;
  #pragma unroll
  for (int kk = 0; kk < 8; kk++) {
    s16x8 pa = *(const s16x8*)(Pb + rowp * 640 + ((kk * 64 + l4 * 16) ^ px));
    #pragma unroll
    for (int m = 0; m < 4; m++) {
      s16x8 bbv = *(const s16x8*)(rvh + (m * 16 + l15) * 256 + kk * 32 + l4 * 8);
      oacc[m] = mfma16(bbv, pa, oacc[m]);
    }
  }
  #pragma unroll
  for (int ks = 0; ks < 2; ks++) {
    s16x8 pa = *(const s16x8*)(Pb + rowp * 640 + 512 + ((ks * 64 + l4 * 16) ^ px));
    #pragma unroll
    for (int m = 0; m < 4; m++) {
      s16x8 bbv = *(const s16x8*)(vTb + (m * 16 + l15) * 64 + ks * 32 + l4 * 8);
      oacc[m] = mfma16(bbv, pa, oacc[m]);
    }
  }
  // oacc[m]: out[d = m*16 + l4*4 + j][t = w*16 + l15] -> packed 8-B stores
  const long obase = ((long)(b * 64 + w * 16 + l15)) * 1024 + h * 64;
  #pragma unroll
  for (int m = 0; m < 4; m++) {
    s16x4 o;
    o[0] = f2bf(oacc[m][0]); o[1] = f2bf(oacc[m][1]);
    o[2] = f2bf(oacc[m][2]); o[3] = f2bf(oacc[m][3]);
    *(s16x4*)(aout + obase + m * 16 + l4 * 4) = o;
  }
}

extern "C" void kernel_launch(void* const* d_in, const int* in_sizes, int n_in,
                              void* d_out, int out_size, void* d_ws, size_t ws_size,
                              hipStream_t stream) {
  const float* x     = (const float*)d_in[0];
  const float* Wq_w  = (const float*)d_in[1];
  const float* Wq_b  = (const float*)d_in[2];
  const float* Wk_w  = (const float*)d_in[3];
  const float* Wk_b  = (const float*)d_in[4];
  const float* Wv_w  = (const float*)d_in[5];
  const float* Wv_b  = (const float*)d_in[6];
  const float* Wo_w  = (const float*)d_in[7];
  const float* Wo_b  = (const float*)d_in[8];
  const float* rel_q = (const float*)d_in[9];
  const float* rel_k = (const float*)d_in[10];
  const float* rel_v = (const float*)d_in[11];
  const int* rel_index = (const int*)d_in[12];
  float* out = (float*)d_out;

  char* ws = (char*)d_ws;
  short* x_bf   = (short*)(ws);                   // 134,217,728 (reused as aout)
  short* qkv_bf = (short*)(ws + 134217728L);      // 402,653,184
  short* wq_bf  = (short*)(ws + 536870912L);      // wq|wk|wv contiguous
  short* wo_bf  = (short*)(ws + 543162368L);
  float* biascat= (float*)(ws + 545259520L);
  short* relqb  = (short*)(ws + 545271808L);
  short* relkb  = (short*)(ws + 545763328L);
  short* relvT  = (short*)(ws + 546254848L);
  float* Dh     = (float*)(ws + 546779136L);
  short* relsum = (short*)(ws + 546794496L);      // 134,217,728
  short* vT     = (short*)(ws + 681012224L);      // 134,217,728
  short* aout   = x_bf;

  cvt_bf16_kernel<<<65536, 256, 0, stream>>>(x, x_bf, 67108864L);
  cvt_bf16_kernel<<<1024, 256, 0, stream>>>(Wq_w, wq_bf, 1048576L);
  cvt_bf16_kernel<<<1024, 256, 0, stream>>>(Wk_w, (short*)(ws + 538968064L), 1048576L);
  cvt_bf16_kernel<<<1024, 256, 0, stream>>>(Wv_w, (short*)(ws + 541065216L), 1048576L);
  cvt_bf16_kernel<<<1024, 256, 0, stream>>>(Wo_w, wo_bf, 1048576L);
  bias_cat_kernel<<<12, 256, 0, stream>>>(Wq_b, Wk_b, Wv_b, biascat);
  prep_rel_kernel<<<3840, 64, 0, stream>>>(rel_q, rel_k, rel_v, relqb, relkb, relvT, Dh);

  gemm256_kernel<1><<<3072, 512, 0, stream>>>(x_bf, wq_bf, biascat, (void*)qkv_bf,
                                              3072, 1024, 1024);
  qrel_kernel<<<16384, 256, 0, stream>>>(qkv_bf, relqb, relkb, Dh, rel_index,
                                         relsum, vT);
  attn_kernel<<<16384, 256, 0, stream>>>(qkv_bf, relsum, relvT, vT, rel_index, aout);
  gemm256_kernel<0><<<1024, 512, 0, stream>>>(aout, wo_bf, Wo_b, (void*)out,
                                              1024, 1024, 1024);
}

// Round 9
// 1567.435 us; speedup vs baseline: 1.1478x; 1.0728x over previous
//
#include <hip/hip_runtime.h>

typedef __attribute__((ext_vector_type(4))) float f32x4;
typedef __attribute__((ext_vector_type(8))) short s16x8;
typedef __attribute__((ext_vector_type(4))) short s16x4;

__device__ __forceinline__ short f2bf(float f) {
  union { float f; unsigned u; } v; v.f = f;
  unsigned r = (v.u + 0x7fffu + ((v.u >> 16) & 1u)) >> 16;
  return (short)(r & 0xffffu);
}
__device__ __forceinline__ float bf2f(short s) {
  union { unsigned u; float f; } v; v.u = ((unsigned)(unsigned short)s) << 16;
  return v.f;
}
__device__ __forceinline__ f32x4 mfma16(s16x8 a, s16x8 b, f32x4 c) {
  return __builtin_amdgcn_mfma_f32_16x16x32_bf16(a, b, c, 0, 0, 0);
}

#define AS1(p) ((__attribute__((address_space(1))) void*)(p))
#define AS3(p) ((__attribute__((address_space(3))) void*)(p))

// ---------------- fp32 -> bf16 convert ----------------
__global__ __launch_bounds__(256) void cvt_bf16_kernel(const float* __restrict__ in,
                                                       short* __restrict__ out, long n) {
  long i = ((long)blockIdx.x * 256 + threadIdx.x) * 4;
  if (i + 4 <= n) {
    f32x4 v = *(const f32x4*)(in + i);
    s16x4 o;
    o[0] = f2bf(v[0]); o[1] = f2bf(v[1]); o[2] = f2bf(v[2]); o[3] = f2bf(v[3]);
    *(s16x4*)(out + i) = o;
  }
}

// ---------------- concat 3 bias vectors ----------------
__global__ __launch_bounds__(256) void bias_cat_kernel(const float* __restrict__ bq,
                                                       const float* __restrict__ bk,
                                                       const float* __restrict__ bv,
                                                       float* __restrict__ o) {
  int i = blockIdx.x * 256 + threadIdx.x;
  if (i < 3072) o[i] = (i < 1024) ? bq[i] : ((i < 2048) ? bk[i - 1024] : bv[i - 2048]);
}

// ---------------- rel table prep ----------------
__global__ __launch_bounds__(64) void prep_rel_kernel(
    const float* __restrict__ rq, const float* __restrict__ rk, const float* __restrict__ rv,
    short* __restrict__ relqb, short* __restrict__ relkb, short* __restrict__ relvT,
    float* __restrict__ Dh) {
  int h = blockIdx.x / 240;
  int r = blockIdx.x % 240;
  int d = threadIdx.x;
  float vq = 0.f, vk = 0.f, vv = 0.f;
  if (r < 225) {
    long o = ((long)h * 225 + r) * 64 + d;
    vq = rq[o]; vk = rk[o]; vv = rv[o];
  }
  relqb[((long)h * 240 + r) * 64 + d] = f2bf(vq);
  relkb[((long)h * 240 + r) * 64 + d] = f2bf(vk);
  relvT[((long)h * 64 + d) * 256 + r] = f2bf(vv);
  if (r < 16) relvT[((long)h * 64 + d) * 256 + 240 + r] = 0;
  float p = vq * vk;
  #pragma unroll
  for (int m = 32; m >= 1; m >>= 1) p += __shfl_xor(p, m);
  if (d == 0) Dh[h * 240 + r] = p;
}

// ============ 256x256 8-phase GEMM: C = A(M x K, lda) @ Bw(N x K)^T + bias ============
// VM0 handoffs (R8 race fix); issue stagger retained for overlap.
#define BAR  __builtin_amdgcn_s_barrier()
#define LGK0 do { asm volatile("s_waitcnt lgkmcnt(0)" ::: "memory"); \
                  __builtin_amdgcn_sched_barrier(0); } while (0)
#define VM0  asm volatile("s_waitcnt vmcnt(0)" ::: "memory")
#define PRIO1 __builtin_amdgcn_s_setprio(1)
#define PRIO0 __builtin_amdgcn_s_setprio(0)

#define STG_A(D, H, KOFF) do { \
    const short* _s = gA + (long)(H) * 128 * ldaL + (KOFF); \
    char* _d = lds + (D) * 32768 + (H) * 16384 + ldsw; \
    __builtin_amdgcn_global_load_lds(AS1(_s), AS3(_d), 16, 0, 0); \
    __builtin_amdgcn_global_load_lds(AS1(_s + 64 * ldaL), AS3(_d + 8192), 16, 0, 0); \
  } while (0)
#define STG_B(D, H, KOFF) do { \
    const short* _s = gB + (long)(H) * 128 * ldbL + (KOFF); \
    char* _d = lds + 65536 + (D) * 32768 + (H) * 16384 + ldsw; \
    __builtin_amdgcn_global_load_lds(AS1(_s), AS3(_d), 16, 0, 0); \
    __builtin_amdgcn_global_load_lds(AS1(_s + 64 * ldbL), AS3(_d + 8192), 16, 0, 0); \
  } while (0)
#define RD_A(D, MIH) do { \
    const char* _b = lds + (D) * 32768 + baseA + (MIH) * 8192; \
    _Pragma("unroll") for (int i = 0; i < 4; i++) { \
      aa[0][i] = *(const s16x8*)(_b + i * 2048 + cax0); \
      aa[1][i] = *(const s16x8*)(_b + i * 2048 + cax1); \
    } } while (0)
#define RD_B(D, NJH) do { \
    const char* _b = lds + (D) * 32768 + baseB + (NJH) * 4096; \
    _Pragma("unroll") for (int j = 0; j < 2; j++) { \
      bb[0][(NJH) * 2 + j] = *(const s16x8*)(_b + j * 2048 + cax0); \
      bb[1][(NJH) * 2 + j] = *(const s16x8*)(_b + j * 2048 + cax1); \
    } } while (0)
#define MM_Q(MIH, NJH) do { \
    _Pragma("unroll") for (int i = 0; i < 4; i++) { \
      _Pragma("unroll") for (int j = 0; j < 2; j++) { \
        f32x4& c = acc[(MIH) * 4 + i][(NJH) * 2 + j]; \
        c = mfma16(bb[0][(NJH) * 2 + j], aa[0][i], c); \
        c = mfma16(bb[1][(NJH) * 2 + j], aa[1][i], c); \
    } } } while (0)

template<int OUT_BF16>
__global__ __launch_bounds__(512, 2) void gemm256_kernel(
    const short* __restrict__ A, const short* __restrict__ Bw,
    const float* __restrict__ bias, void* __restrict__ Cout,
    int N, int K, int lda) {
  __shared__ __attribute__((aligned(16))) char lds[131072];
  const int tid = threadIdx.x, lane = tid & 63, w = tid >> 6;
  const int wr = w >> 2, wc = w & 3;
  const int l15 = lane & 15, l4 = lane >> 4;
  const int nbn = N >> 8;
  const int nwg = gridDim.x, bid = blockIdx.x;
  const int swz = ((bid & 7) * (nwg >> 3)) + (bid >> 3);   // XCD swizzle (nwg%8==0)
  const int bm = swz / nbn, bn = swz % nbn;

  const int srow = tid >> 3;
  const int scol = ((tid & 7) ^ (srow & 7)) * 8;           // pre-swizzled source chunk
  const long ldaL = lda, ldbL = K;
  const short* gA = A  + ((long)(bm * 256 + srow)) * ldaL + scol;
  const short* gB = Bw + ((long)(bn * 256 + srow)) * ldbL + scol;
  const int ldsw = w * 1024;

  const int baseA = (wr * 128 + l15) * 128;
  const int baseB = 65536 + (wc * 64 + l15) * 128;
  const int cax0 = ((l4) ^ (l15 & 7)) * 16;
  const int cax1 = ((4 + l4) ^ (l15 & 7)) * 16;

  f32x4 acc[8][4];
  #pragma unroll
  for (int i = 0; i < 8; i++)
    #pragma unroll
    for (int j = 0; j < 4; j++) acc[i][j] = (f32x4){0.f, 0.f, 0.f, 0.f};
  s16x8 aa[2][4], bb[2][4];

  STG_A(0, 0, 0); STG_A(0, 1, 0); STG_B(0, 0, 0); STG_B(0, 1, 0);
  STG_B(1, 0, 64); STG_B(1, 1, 64);
  VM0;
  BAR;

  const int NT = K >> 6;
  for (int kt = 0; kt < NT; kt += 2) {
    const int k1 = (kt + 1) << 6, k2 = (kt + 2) << 6, k3 = (kt + 3) << 6;
    const bool full = (kt + 2) < NT;
    STG_A(1, 0, k1);
    RD_A(0, 0); RD_B(0, 0);
    BAR; LGK0; PRIO1; MM_Q(0, 0); PRIO0; BAR;
    STG_A(1, 1, k1);
    RD_B(0, 1);
    BAR; LGK0; PRIO1; MM_Q(0, 1); PRIO0; BAR;
    if (full) STG_B(0, 0, k2);
    RD_A(0, 1);
    BAR; LGK0; PRIO1; MM_Q(1, 0); PRIO0; BAR;
    if (full) STG_B(0, 1, k2);
    BAR; LGK0; PRIO1; MM_Q(1, 1); PRIO0;
    VM0;
    BAR;
    if (full) STG_A(0, 0, k2);
    RD_A(1, 0); RD_B(1, 0);
    BAR; LGK0; PRIO1; MM_Q(0, 0); PRIO0; BAR;
    if (full) STG_A(0, 1, k2);
    RD_B(1, 1);
    BAR; LGK0; PRIO1; MM_Q(0, 1); PRIO0; BAR;
    if (full) STG_B(1, 0, k3);
    RD_A(1, 1);
    BAR; LGK0; PRIO1; MM_Q(1, 0); PRIO0; BAR;
    if (full) STG_B(1, 1, k3);
    BAR; LGK0; PRIO1; MM_Q(1, 1); PRIO0;
    VM0;
    BAR;
  }

  const long crow = (long)bm * 256 + wr * 128;
  const int ccol = bn * 256 + wc * 64;
  #pragma unroll
  for (int nj = 0; nj < 4; nj++) {
    const int colb = ccol + nj * 16 + l4 * 4;
    const f32x4 bv4 = *(const f32x4*)&bias[colb];
    #pragma unroll
    for (int mi = 0; mi < 8; mi++) {
      const long row = crow + mi * 16 + l15;
      f32x4 v = acc[mi][nj] + bv4;
      if (OUT_BF16) {
        s16x4 o;
        o[0] = f2bf(v[0]); o[1] = f2bf(v[1]); o[2] = f2bf(v[2]); o[3] = f2bf(v[3]);
        *(s16x4*)((short*)Cout + row * N + colb) = o;
      } else {
        *(f32x4*)((float*)Cout + row * N + colb) = v;
      }
    }
  }
}

// ---------------- fully fused relative attention (qr/kr + gather + softmax + PV) ------
// One block per (b,h), 4 waves, 2 barriers.  LDS phase overlay:
//   phase 1: region = qrs[4 waves][16][512B] (qr, swizzled) | +32768: krs[64][512B]
//   phase 2: region = Pb[64][640B] (P 512B + attn 128B per row)
// vts (v^T, 8KB, swizzled) is separate and persists.
// Swapped-operand qr/kr: mfma(rel_frag, q_frag) -> reg j indexes consecutive r
// -> 8-B vector LDS writes.  idx injective per t -> P scatter collision-free.
__global__ __launch_bounds__(256, 2) void attn_kernel(
    const short* __restrict__ qkv, const short* __restrict__ relqb,
    const short* __restrict__ relkb, const float* __restrict__ Dh,
    const short* __restrict__ relvT, const int* __restrict__ rel_index,
    short* __restrict__ aout) {
  __shared__ __attribute__((aligned(16))) char region[65536];
  __shared__ __attribute__((aligned(16))) char vts[8192];

  const int tid = threadIdx.x, lane = tid & 63, w = tid >> 6;
  const int l15 = lane & 15, l4 = lane >> 4;
  const int bh = blockIdx.x, b = bh >> 4, h = bh & 15;
  const f32x4 zero = {0.f, 0.f, 0.f, 0.f};

  // ---- stage v^T (scalar transpose writes into swizzled vts[d][128B]) ----
  {
    const int t = tid >> 2, c0 = (tid & 3) * 16;
    const long g = ((long)(b * 64 + t)) * 3072 + 2048 + h * 64 + c0;
    s16x8 v0 = *(const s16x8*)(qkv + g);
    s16x8 v1 = *(const s16x8*)(qkv + g + 8);
    #pragma unroll
    for (int i = 0; i < 8; i++) {
      const int d = c0 + i;
      *(short*)(vts + d * 128 + ((t * 2) ^ ((d & 7) << 4))) = v0[i];
    }
    #pragma unroll
    for (int i = 0; i < 8; i++) {
      const int d = c0 + 8 + i;
      *(short*)(vts + d * 128 + ((t * 2) ^ ((d & 7) << 4))) = v1[i];
    }
  }

  // ---- q,k fragments ----
  const long qbase = ((long)(b * 64 + w * 16 + l15)) * 3072 + h * 64;
  s16x8 aq0 = *(const s16x8*)(qkv + qbase + l4 * 8);
  s16x8 aq1 = *(const s16x8*)(qkv + qbase + 32 + l4 * 8);
  s16x8 ak0 = *(const s16x8*)(qkv + qbase + 1024 + l4 * 8);       // k row s=w*16+l15
  s16x8 ak1 = *(const s16x8*)(qkv + qbase + 1056 + l4 * 8);

  // ---- S = q @ k^T ----
  f32x4 sacc[4];
  sacc[0] = sacc[1] = sacc[2] = sacc[3] = zero;
  #pragma unroll
  for (int n = 0; n < 4; n++) {
    const long kb = ((long)(b * 64 + n * 16 + l15)) * 3072 + 1024 + h * 64;
    s16x8 b0 = *(const s16x8*)(qkv + kb + l4 * 8);
    s16x8 b1 = *(const s16x8*)(qkv + kb + 32 + l4 * 8);
    sacc[n] = mfma16(aq0, b0, sacc[n]);
    sacc[n] = mfma16(aq1, b1, sacc[n]);
  }

  // ---- qr (+Dh) and kr, swapped operands -> 8-B vector LDS writes ----
  char* qw  = region + w * 8192;    // wave-own [16][512B]
  char* krs = region + 32768;       // [64][512B]
  const short* rkh = relkb + (long)h * 240 * 64;
  const short* rqh = relqb + (long)h * 240 * 64;
  const int rowk = w * 16 + l15;    // krs global row (== qw local row l15 mod 8 swizzle)
  #pragma unroll
  for (int nj = 0; nj < 15; nj++) {
    const int rr = nj * 16 + l15;
    s16x8 b0 = *(const s16x8*)(rkh + rr * 64 + l4 * 8);
    s16x8 b1 = *(const s16x8*)(rkh + rr * 64 + 32 + l4 * 8);
    f32x4 t0 = mfma16(b1, aq1, mfma16(b0, aq0, zero));   // qr[r=nj*16+l4*4+j][t=w*16+l15]
    s16x8 c0v = *(const s16x8*)(rqh + rr * 64 + l4 * 8);
    s16x8 c1v = *(const s16x8*)(rqh + rr * 64 + 32 + l4 * 8);
    f32x4 t1 = mfma16(c1v, ak1, mfma16(c0v, ak0, zero)); // kr[r][s=w*16+l15]
    const f32x4 dv4 = *(const f32x4*)&Dh[h * 240 + nj * 16 + l4 * 4];
    const int cb = (nj * 32 + l4 * 8) ^ ((l15 & 7) << 4);
    s16x4 q4, k4;
    #pragma unroll
    for (int j = 0; j < 4; j++) { q4[j] = f2bf(t0[j] + dv4[j]); k4[j] = f2bf(t1[j]); }
    *(s16x4*)(qw + l15 * 512 + cb) = q4;
    *(s16x4*)(krs + rowk * 512 + cb) = k4;
  }
  __syncthreads();   // barrier 1: krs + vts visible

  // ---- gather + logits + softmax ----
  #pragma unroll
  for (int n = 0; n < 4; n++)
    #pragma unroll
    for (int j = 0; j < 4; j++) {
      const int tl = l4 * 4 + j;
      const int t = w * 16 + tl, s = n * 16 + l15;
      const int r = rel_index[t * 64 + s];
      const float qg = bf2f(*(const short*)(qw + tl * 512 + ((r * 2) ^ ((tl & 7) << 4))));
      const float kg = bf2f(*(const short*)(krs + s * 512 + ((r * 2) ^ ((s & 7) << 4))));
      sacc[n][j] = (sacc[n][j] + qg + kg) * 0.125f;
    }
  float att[4][4];
  #pragma unroll
  for (int j = 0; j < 4; j++) {
    float m = fmaxf(fmaxf(sacc[0][j], sacc[1][j]), fmaxf(sacc[2][j], sacc[3][j]));
    m = fmaxf(m, __shfl_xor(m, 1));
    m = fmaxf(m, __shfl_xor(m, 2));
    m = fmaxf(m, __shfl_xor(m, 4));
    m = fmaxf(m, __shfl_xor(m, 8));
    float sum = 0.f;
    #pragma unroll
    for (int n = 0; n < 4; n++) { att[n][j] = __expf(sacc[n][j] - m); sum += att[n][j]; }
    sum += __shfl_xor(sum, 1);
    sum += __shfl_xor(sum, 2);
    sum += __shfl_xor(sum, 4);
    sum += __shfl_xor(sum, 8);
    const float inv = 1.f / sum;
    #pragma unroll
    for (int n = 0; n < 4; n++) att[n][j] *= inv;
  }
  __syncthreads();   // barrier 2: all qrs/krs reads done -> region reusable as Pb

  // ---- zero wave-own P rows, scatter P + attn (swizzled) ----
  char* Pb = region;
  {
    s16x8 z = {0, 0, 0, 0, 0, 0, 0, 0};
    #pragma unroll
    for (int i = 0; i < 8; i++) {
      const int c = lane + 64 * i;
      *(s16x8*)(Pb + (w * 16 + (c >> 5)) * 640 + (c & 31) * 16) = z;
    }
  }
  #pragma unroll
  for (int n = 0; n < 4; n++)
    #pragma unroll
    for (int j = 0; j < 4; j++) {
      const int t = w * 16 + l4 * 4 + j, s = n * 16 + l15;
      const int r = rel_index[t * 64 + s];
      const int sw = (t & 7) << 4;
      const short a = f2bf(att[n][j]);
      *(short*)(Pb + t * 640 + ((r * 2) ^ sw)) = a;
      *(short*)(Pb + t * 640 + 512 + ((s * 2) ^ sw)) = a;
    }

  // ---- out^T = [relv^T ; v^T] x [P | attn]^T ----
  f32x4 oacc[4];
  oacc[0] = oacc[1] = oacc[2] = oacc[3] = zero;
  const int rowp = w * 16 + l15, px = (rowp & 7) << 4;
  const short* rvh = relvT + (long)h * 16384;
  #pragma unroll
  for (int kk = 0; kk < 8; kk++) {
    s16x8 pa = *(const s16x8*)(Pb + rowp * 640 + ((kk * 64 + l4 * 16) ^ px));
    #pragma unroll
    for (int m = 0; m < 4; m++) {
      s16x8 bbv = *(const s16x8*)(rvh + (m * 16 + l15) * 256 + kk * 32 + l4 * 8);
      oacc[m] = mfma16(bbv, pa, oacc[m]);
    }
  }
  #pragma unroll
  for (int ks = 0; ks < 2; ks++) {
    s16x8 pa = *(const s16x8*)(Pb + rowp * 640 + 512 + ((ks * 64 + l4 * 16) ^ px));
    #pragma unroll
    for (int m = 0; m < 4; m++) {
      const int d = m * 16 + l15;
      s16x8 bbv = *(const s16x8*)(vts + d * 128 + ((ks * 64 + l4 * 16) ^ ((d & 7) << 4)));
      oacc[m] = mfma16(bbv, pa, oacc[m]);
    }
  }
  // oacc[m]: out[d = m*16 + l4*4 + j][t = w*16 + l15] -> packed 8-B stores
  const long obase = ((long)(b * 64 + w * 16 + l15)) * 1024 + h * 64;
  #pragma unroll
  for (int m = 0; m < 4; m++) {
    s16x4 o;
    o[0] = f2bf(oacc[m][0]); o[1] = f2bf(oacc[m][1]);
    o[2] = f2bf(oacc[m][2]); o[3] = f2bf(oacc[m][3]);
    *(s16x4*)(aout + obase + m * 16 + l4 * 4) = o;
  }
}

extern "C" void kernel_launch(void* const* d_in, const int* in_sizes, int n_in,
                              void* d_out, int out_size, void* d_ws, size_t ws_size,
                              hipStream_t stream) {
  const float* x     = (const float*)d_in[0];
  const float* Wq_w  = (const float*)d_in[1];
  const float* Wq_b  = (const float*)d_in[2];
  const float* Wk_w  = (const float*)d_in[3];
  const float* Wk_b  = (const float*)d_in[4];
  const float* Wv_w  = (const float*)d_in[5];
  const float* Wv_b  = (const float*)d_in[6];
  const float* Wo_w  = (const float*)d_in[7];
  const float* Wo_b  = (const float*)d_in[8];
  const float* rel_q = (const float*)d_in[9];
  const float* rel_k = (const float*)d_in[10];
  const float* rel_v = (const float*)d_in[11];
  const int* rel_index = (const int*)d_in[12];
  float* out = (float*)d_out;

  char* ws = (char*)d_ws;
  short* x_bf   = (short*)(ws);                   // 134,217,728 (reused as aout)
  short* qkv_bf = (short*)(ws + 134217728L);      // 402,653,184
  short* wq_bf  = (short*)(ws + 536870912L);      // wq|wk|wv contiguous
  short* wo_bf  = (short*)(ws + 543162368L);
  float* biascat= (float*)(ws + 545259520L);
  short* relqb  = (short*)(ws + 545271808L);
  short* relkb  = (short*)(ws + 545763328L);
  short* relvT  = (short*)(ws + 546254848L);
  float* Dh     = (float*)(ws + 546779136L);
  short* aout   = x_bf;

  cvt_bf16_kernel<<<65536, 256, 0, stream>>>(x, x_bf, 67108864L);
  cvt_bf16_kernel<<<1024, 256, 0, stream>>>(Wq_w, wq_bf, 1048576L);
  cvt_bf16_kernel<<<1024, 256, 0, stream>>>(Wk_w, (short*)(ws + 538968064L), 1048576L);
  cvt_bf16_kernel<<<1024, 256, 0, stream>>>(Wv_w, (short*)(ws + 541065216L), 1048576L);
  cvt_bf16_kernel<<<1024, 256, 0, stream>>>(Wo_w, wo_bf, 1048576L);
  bias_cat_kernel<<<12, 256, 0, stream>>>(Wq_b, Wk_b, Wv_b, biascat);
  prep_rel_kernel<<<3840, 64, 0, stream>>>(rel_q, rel_k, rel_v, relqb, relkb, relvT, Dh);

  gemm256_kernel<1><<<3072, 512, 0, stream>>>(x_bf, wq_bf, biascat, (void*)qkv_bf,
                                              3072, 1024, 1024);
  attn_kernel<<<16384, 256, 0, stream>>>(qkv_bf, relqb, relkb, Dh, relvT, rel_index, aout);
  gemm256_kernel<0><<<1024, 512, 0, stream>>>(aout, wo_bf, Wo_b, (void*)out,
                                              1024, 1024, 1024);
}

// Round 10
// 1492.587 us; speedup vs baseline: 1.2053x; 1.0501x over previous
//
#include <hip/hip_runtime.h>

typedef __attribute__((ext_vector_type(4))) float f32x4;
typedef __attribute__((ext_vector_type(8))) short s16x8;
typedef __attribute__((ext_vector_type(4))) short s16x4;

__device__ __forceinline__ short f2bf(float f) {
  union { float f; unsigned u; } v; v.f = f;
  unsigned r = (v.u + 0x7fffu + ((v.u >> 16) & 1u)) >> 16;
  return (short)(r & 0xffffu);
}
__device__ __forceinline__ float bf2f(short s) {
  union { unsigned u; float f; } v; v.u = ((unsigned)(unsigned short)s) << 16;
  return v.f;
}
__device__ __forceinline__ f32x4 mfma16(s16x8 a, s16x8 b, f32x4 c) {
  return __builtin_amdgcn_mfma_f32_16x16x32_bf16(a, b, c, 0, 0, 0);
}

#define AS1(p) ((__attribute__((address_space(1))) void*)(p))
#define AS3(p) ((__attribute__((address_space(3))) void*)(p))

// ---------------- fp32 -> bf16 convert ----------------
__global__ __launch_bounds__(256) void cvt_bf16_kernel(const float* __restrict__ in,
                                                       short* __restrict__ out, long n) {
  long i = ((long)blockIdx.x * 256 + threadIdx.x) * 4;
  if (i + 4 <= n) {
    f32x4 v = *(const f32x4*)(in + i);
    s16x4 o;
    o[0] = f2bf(v[0]); o[1] = f2bf(v[1]); o[2] = f2bf(v[2]); o[3] = f2bf(v[3]);
    *(s16x4*)(out + i) = o;
  }
}

// ---------------- concat 3 bias vectors ----------------
__global__ __launch_bounds__(256) void bias_cat_kernel(const float* __restrict__ bq,
                                                       const float* __restrict__ bk,
                                                       const float* __restrict__ bv,
                                                       float* __restrict__ o) {
  int i = blockIdx.x * 256 + threadIdx.x;
  if (i < 3072) o[i] = (i < 1024) ? bq[i] : ((i < 2048) ? bk[i - 1024] : bv[i - 2048]);
}

// ---------------- rel table prep ----------------
__global__ __launch_bounds__(64) void prep_rel_kernel(
    const float* __restrict__ rq, const float* __restrict__ rk, const float* __restrict__ rv,
    short* __restrict__ relqb, short* __restrict__ relkb, short* __restrict__ relvT,
    float* __restrict__ Dh) {
  int h = blockIdx.x / 240;
  int r = blockIdx.x % 240;
  int d = threadIdx.x;
  float vq = 0.f, vk = 0.f, vv = 0.f;
  if (r < 225) {
    long o = ((long)h * 225 + r) * 64 + d;
    vq = rq[o]; vk = rk[o]; vv = rv[o];
  }
  relqb[((long)h * 240 + r) * 64 + d] = f2bf(vq);
  relkb[((long)h * 240 + r) * 64 + d] = f2bf(vk);
  relvT[((long)h * 64 + d) * 256 + r] = f2bf(vv);
  if (r < 16) relvT[((long)h * 64 + d) * 256 + 240 + r] = 0;
  float p = vq * vk;
  #pragma unroll
  for (int m = 32; m >= 1; m >>= 1) p += __shfl_xor(p, m);
  if (d == 0) Dh[h * 240 + r] = p;
}

// ============ 256x256 8-phase GEMM: C = A(M x K, lda) @ Bw(N x K)^T + bias ============
// VM0 handoffs (R8 race fix); issue stagger retained for overlap.
#define BAR  __builtin_amdgcn_s_barrier()
#define LGK0 do { asm volatile("s_waitcnt lgkmcnt(0)" ::: "memory"); \
                  __builtin_amdgcn_sched_barrier(0); } while (0)
#define VM0  asm volatile("s_waitcnt vmcnt(0)" ::: "memory")
#define PRIO1 __builtin_amdgcn_s_setprio(1)
#define PRIO0 __builtin_amdgcn_s_setprio(0)

#define STG_A(D, H, KOFF) do { \
    const short* _s = gA + (long)(H) * 128 * ldaL + (KOFF); \
    char* _d = lds + (D) * 32768 + (H) * 16384 + ldsw; \
    __builtin_amdgcn_global_load_lds(AS1(_s), AS3(_d), 16, 0, 0); \
    __builtin_amdgcn_global_load_lds(AS1(_s + 64 * ldaL), AS3(_d + 8192), 16, 0, 0); \
  } while (0)
#define STG_B(D, H, KOFF) do { \
    const short* _s = gB + (long)(H) * 128 * ldbL + (KOFF); \
    char* _d = lds + 65536 + (D) * 32768 + (H) * 16384 + ldsw; \
    __builtin_amdgcn_global_load_lds(AS1(_s), AS3(_d), 16, 0, 0); \
    __builtin_amdgcn_global_load_lds(AS1(_s + 64 * ldbL), AS3(_d + 8192), 16, 0, 0); \
  } while (0)
#define RD_A(D, MIH) do { \
    const char* _b = lds + (D) * 32768 + baseA + (MIH) * 8192; \
    _Pragma("unroll") for (int i = 0; i < 4; i++) { \
      aa[0][i] = *(const s16x8*)(_b + i * 2048 + cax0); \
      aa[1][i] = *(const s16x8*)(_b + i * 2048 + cax1); \
    } } while (0)
#define RD_B(D, NJH) do { \
    const char* _b = lds + (D) * 32768 + baseB + (NJH) * 4096; \
    _Pragma("unroll") for (int j = 0; j < 2; j++) { \
      bb[0][(NJH) * 2 + j] = *(const s16x8*)(_b + j * 2048 + cax0); \
      bb[1][(NJH) * 2 + j] = *(const s16x8*)(_b + j * 2048 + cax1); \
    } } while (0)
#define MM_Q(MIH, NJH) do { \
    _Pragma("unroll") for (int i = 0; i < 4; i++) { \
      _Pragma("unroll") for (int j = 0; j < 2; j++) { \
        f32x4& c = acc[(MIH) * 4 + i][(NJH) * 2 + j]; \
        c = mfma16(bb[0][(NJH) * 2 + j], aa[0][i], c); \
        c = mfma16(bb[1][(NJH) * 2 + j], aa[1][i], c); \
    } } } while (0)

template<int OUT_BF16>
__global__ __launch_bounds__(512, 2) void gemm256_kernel(
    const short* __restrict__ A, const short* __restrict__ Bw,
    const float* __restrict__ bias, void* __restrict__ Cout,
    int N, int K, int lda) {
  __shared__ __attribute__((aligned(16))) char lds[131072];
  const int tid = threadIdx.x, lane = tid & 63, w = tid >> 6;
  const int wr = w >> 2, wc = w & 3;
  const int l15 = lane & 15, l4 = lane >> 4;
  const int nbn = N >> 8;
  const int nwg = gridDim.x, bid = blockIdx.x;
  const int swz = ((bid & 7) * (nwg >> 3)) + (bid >> 3);   // XCD swizzle (nwg%8==0)
  const int bm = swz / nbn, bn = swz % nbn;

  const int srow = tid >> 3;
  const int scol = ((tid & 7) ^ (srow & 7)) * 8;           // pre-swizzled source chunk
  const long ldaL = lda, ldbL = K;
  const short* gA = A  + ((long)(bm * 256 + srow)) * ldaL + scol;
  const short* gB = Bw + ((long)(bn * 256 + srow)) * ldbL + scol;
  const int ldsw = w * 1024;

  const int baseA = (wr * 128 + l15) * 128;
  const int baseB = 65536 + (wc * 64 + l15) * 128;
  const int cax0 = ((l4) ^ (l15 & 7)) * 16;
  const int cax1 = ((4 + l4) ^ (l15 & 7)) * 16;

  f32x4 acc[8][4];
  #pragma unroll
  for (int i = 0; i < 8; i++)
    #pragma unroll
    for (int j = 0; j < 4; j++) acc[i][j] = (f32x4){0.f, 0.f, 0.f, 0.f};
  s16x8 aa[2][4], bb[2][4];

  STG_A(0, 0, 0); STG_A(0, 1, 0); STG_B(0, 0, 0); STG_B(0, 1, 0);
  STG_B(1, 0, 64); STG_B(1, 1, 64);
  VM0;
  BAR;

  const int NT = K >> 6;
  for (int kt = 0; kt < NT; kt += 2) {
    const int k1 = (kt + 1) << 6, k2 = (kt + 2) << 6, k3 = (kt + 3) << 6;
    const bool full = (kt + 2) < NT;
    STG_A(1, 0, k1);
    RD_A(0, 0); RD_B(0, 0);
    BAR; LGK0; PRIO1; MM_Q(0, 0); PRIO0; BAR;
    STG_A(1, 1, k1);
    RD_B(0, 1);
    BAR; LGK0; PRIO1; MM_Q(0, 1); PRIO0; BAR;
    if (full) STG_B(0, 0, k2);
    RD_A(0, 1);
    BAR; LGK0; PRIO1; MM_Q(1, 0); PRIO0; BAR;
    if (full) STG_B(0, 1, k2);
    BAR; LGK0; PRIO1; MM_Q(1, 1); PRIO0;
    VM0;
    BAR;
    if (full) STG_A(0, 0, k2);
    RD_A(1, 0); RD_B(1, 0);
    BAR; LGK0; PRIO1; MM_Q(0, 0); PRIO0; BAR;
    if (full) STG_A(0, 1, k2);
    RD_B(1, 1);
    BAR; LGK0; PRIO1; MM_Q(0, 1); PRIO0; BAR;
    if (full) STG_B(1, 0, k3);
    RD_A(1, 1);
    BAR; LGK0; PRIO1; MM_Q(1, 0); PRIO0; BAR;
    if (full) STG_B(1, 1, k3);
    BAR; LGK0; PRIO1; MM_Q(1, 1); PRIO0;
    VM0;
    BAR;
  }

  const long crow = (long)bm * 256 + wr * 128;
  const int ccol = bn * 256 + wc * 64;
  #pragma unroll
  for (int nj = 0; nj < 4; nj++) {
    const int colb = ccol + nj * 16 + l4 * 4;
    const f32x4 bv4 = *(const f32x4*)&bias[colb];
    #pragma unroll
    for (int mi = 0; mi < 8; mi++) {
      const long row = crow + mi * 16 + l15;
      f32x4 v = acc[mi][nj] + bv4;
      if (OUT_BF16) {
        s16x4 o;
        o[0] = f2bf(v[0]); o[1] = f2bf(v[1]); o[2] = f2bf(v[2]); o[3] = f2bf(v[3]);
        *(s16x4*)((short*)Cout + row * N + colb) = o;
      } else {
        *(f32x4*)((float*)Cout + row * N + colb) = v;
      }
    }
  }
}

// ---------------- fused relative attention, 8-wave role split ----------------
// One block per (b,h), 512 threads.  Waves 0-3: S + qr (own 16 t-rows).
// Waves 4-7: v^T staging + kr (own 16 s-rows).  3 x __syncthreads.
// LDS overlay: phase 1 region = qrs[4][16][512B] | krs[64][512B] (64KB);
// phase 2 region = Pb[64][640B].  vts (8KB, swizzled) persists.
__global__ __launch_bounds__(512, 4) void attn_kernel(
    const short* __restrict__ qkv, const short* __restrict__ relqb,
    const short* __restrict__ relkb, const float* __restrict__ Dh,
    const short* __restrict__ relvT, const int* __restrict__ rel_index,
    short* __restrict__ aout) {
  __shared__ __attribute__((aligned(16))) char region[65536];
  __shared__ __attribute__((aligned(16))) char vts[8192];

  const int tid = threadIdx.x, lane = tid & 63, w = tid >> 6;
  const int l15 = lane & 15, l4 = lane >> 4;
  const int bh = blockIdx.x, b = bh >> 4, h = bh & 15;
  const f32x4 zero = {0.f, 0.f, 0.f, 0.f};

  char* qw  = region + (w & 3) * 8192;   // wave-own qr [16][512B] (waves 0-3)
  char* krs = region + 32768;            // kr [64][512B] (written by waves 4-7)

  f32x4 sacc[4];
  float att[4][4];
  int idxr[16];
  s16x8 aq0, aq1;

  if (w < 4) {
    // idx hoist (used in gather AND scatter)
    #pragma unroll
    for (int n = 0; n < 4; n++)
      #pragma unroll
      for (int j = 0; j < 4; j++)
        idxr[n * 4 + j] = rel_index[(w * 16 + l4 * 4 + j) * 64 + n * 16 + l15];
    const long qb = ((long)(b * 64 + w * 16 + l15)) * 3072 + h * 64;
    aq0 = *(const s16x8*)(qkv + qb + l4 * 8);
    aq1 = *(const s16x8*)(qkv + qb + 32 + l4 * 8);
    // S = q @ k^T
    sacc[0] = sacc[1] = sacc[2] = sacc[3] = zero;
    #pragma unroll
    for (int n = 0; n < 4; n++) {
      const long kb = ((long)(b * 64 + n * 16 + l15)) * 3072 + 1024 + h * 64;
      s16x8 b0 = *(const s16x8*)(qkv + kb + l4 * 8);
      s16x8 b1 = *(const s16x8*)(qkv + kb + 32 + l4 * 8);
      sacc[n] = mfma16(aq0, b0, sacc[n]);
      sacc[n] = mfma16(aq1, b1, sacc[n]);
    }
    // qr (+Dh), swapped operands -> 8-B vector LDS writes, wave-own rows
    const short* rkh = relkb + (long)h * 240 * 64;
    #pragma unroll
    for (int nj = 0; nj < 15; nj++) {
      const int rr = nj * 16 + l15;
      s16x8 b0 = *(const s16x8*)(rkh + rr * 64 + l4 * 8);
      s16x8 b1 = *(const s16x8*)(rkh + rr * 64 + 32 + l4 * 8);
      f32x4 t0 = mfma16(b1, aq1, mfma16(b0, aq0, zero));
      const f32x4 dv4 = *(const f32x4*)&Dh[h * 240 + nj * 16 + l4 * 4];
      const int cb = (nj * 32 + l4 * 8) ^ ((l15 & 7) << 4);
      s16x4 q4;
      #pragma unroll
      for (int j = 0; j < 4; j++) q4[j] = f2bf(t0[j] + dv4[j]);
      *(s16x4*)(qw + l15 * 512 + cb) = q4;
    }
  } else {
    // v^T staging (256 threads cover 64 rows x 4 col-chunks)
    const int tid2 = tid - 256;
    const int tv = tid2 >> 2, c0 = (tid2 & 3) * 16;
    const long g = ((long)(b * 64 + tv)) * 3072 + 2048 + h * 64 + c0;
    s16x8 v0 = *(const s16x8*)(qkv + g);
    s16x8 v1 = *(const s16x8*)(qkv + g + 8);
    #pragma unroll
    for (int i = 0; i < 8; i++) {
      const int d = c0 + i;
      *(short*)(vts + d * 128 + ((tv * 2) ^ ((d & 7) << 4))) = v0[i];
    }
    #pragma unroll
    for (int i = 0; i < 8; i++) {
      const int d = c0 + 8 + i;
      *(short*)(vts + d * 128 + ((tv * 2) ^ ((d & 7) << 4))) = v1[i];
    }
    // kr, swapped operands, own s-rows
    const int wl = w - 4;
    const int rowk = wl * 16 + l15;
    const long kb2 = ((long)(b * 64 + rowk)) * 3072 + 1024 + h * 64;
    s16x8 ak0 = *(const s16x8*)(qkv + kb2 + l4 * 8);
    s16x8 ak1 = *(const s16x8*)(qkv + kb2 + 32 + l4 * 8);
    const short* rqh = relqb + (long)h * 240 * 64;
    #pragma unroll
    for (int nj = 0; nj < 15; nj++) {
      const int rr = nj * 16 + l15;
      s16x8 c0v = *(const s16x8*)(rqh + rr * 64 + l4 * 8);
      s16x8 c1v = *(const s16x8*)(rqh + rr * 64 + 32 + l4 * 8);
      f32x4 t1 = mfma16(c1v, ak1, mfma16(c0v, ak0, zero));
      const int cb = (nj * 32 + l4 * 8) ^ ((l15 & 7) << 4);
      s16x4 k4;
      #pragma unroll
      for (int j = 0; j < 4; j++) k4[j] = f2bf(t1[j]);
      *(s16x4*)(krs + rowk * 512 + cb) = k4;
    }
  }
  __syncthreads();   // barrier 1: qrs/krs/vts visible

  if (w < 4) {
    // gather + logits + softmax
    #pragma unroll
    for (int n = 0; n < 4; n++)
      #pragma unroll
      for (int j = 0; j < 4; j++) {
        const int tl = l4 * 4 + j;
        const int s = n * 16 + l15;
        const int r = idxr[n * 4 + j];
        const float qg = bf2f(*(const short*)(qw + tl * 512 + ((r * 2) ^ ((tl & 7) << 4))));
        const float kg = bf2f(*(const short*)(krs + s * 512 + ((r * 2) ^ ((s & 7) << 4))));
        sacc[n][j] = (sacc[n][j] + qg + kg) * 0.125f;
      }
    #pragma unroll
    for (int j = 0; j < 4; j++) {
      float m = fmaxf(fmaxf(sacc[0][j], sacc[1][j]), fmaxf(sacc[2][j], sacc[3][j]));
      m = fmaxf(m, __shfl_xor(m, 1));
      m = fmaxf(m, __shfl_xor(m, 2));
      m = fmaxf(m, __shfl_xor(m, 4));
      m = fmaxf(m, __shfl_xor(m, 8));
      float sum = 0.f;
      #pragma unroll
      for (int n = 0; n < 4; n++) { att[n][j] = __expf(sacc[n][j] - m); sum += att[n][j]; }
      sum += __shfl_xor(sum, 1);
      sum += __shfl_xor(sum, 2);
      sum += __shfl_xor(sum, 4);
      sum += __shfl_xor(sum, 8);
      const float inv = 1.f / sum;
      #pragma unroll
      for (int n = 0; n < 4; n++) att[n][j] *= inv;
    }
  }
  __syncthreads();   // barrier 2: all qrs/krs reads done -> region reusable as Pb

  char* Pb = region;
  if (w < 4) {
    // zero wave-own P rows, scatter P + attn (swizzled, collision-free)
    s16x8 z = {0, 0, 0, 0, 0, 0, 0, 0};
    #pragma unroll
    for (int i = 0; i < 8; i++) {
      const int c = lane + 64 * i;
      *(s16x8*)(Pb + (w * 16 + (c >> 5)) * 640 + (c & 31) * 16) = z;
    }
    #pragma unroll
    for (int n = 0; n < 4; n++)
      #pragma unroll
      for (int j = 0; j < 4; j++) {
        const int t = w * 16 + l4 * 4 + j, s = n * 16 + l15;
        const int r = idxr[n * 4 + j];
        const int sw = (t & 7) << 4;
        const short a = f2bf(att[n][j]);
        *(short*)(Pb + t * 640 + ((r * 2) ^ sw)) = a;
        *(short*)(Pb + t * 640 + 512 + ((s * 2) ^ sw)) = a;
      }
  }
  __syncthreads();   // barrier 3: Pb complete

  // PV: wave w owns t-column tc = w&3 and d-blocks mb, mb+1 (mb = (w>>2)*2)
  const int tc = w & 3, mb = (w >> 2) * 2;
  const int rowp = tc * 16 + l15, px = (rowp & 7) << 4;
  const short* rvh = relvT + (long)h * 16384;
  f32x4 oacc0 = zero, oacc1 = zero;
  #pragma unroll
  for (int kk = 0; kk < 8; kk++) {
    s16x8 pa = *(const s16x8*)(Pb + rowp * 640 + ((kk * 64 + l4 * 16) ^ px));
    s16x8 bv0 = *(const s16x8*)(rvh + ((mb + 0) * 16 + l15) * 256 + kk * 32 + l4 * 8);
    s16x8 bv1 = *(const s16x8*)(rvh + ((mb + 1) * 16 + l15) * 256 + kk * 32 + l4 * 8);
    oacc0 = mfma16(bv0, pa, oacc0);
    oacc1 = mfma16(bv1, pa, oacc1);
  }
  #pragma unroll
  for (int ks = 0; ks < 2; ks++) {
    s16x8 pa = *(const s16x8*)(Pb + rowp * 640 + 512 + ((ks * 64 + l4 * 16) ^ px));
    const int d0 = (mb + 0) * 16 + l15;
    const int d1 = (mb + 1) * 16 + l15;
    s16x8 bv0 = *(const s16x8*)(vts + d0 * 128 + ((ks * 64 + l4 * 16) ^ ((d0 & 7) << 4)));
    s16x8 bv1 = *(const s16x8*)(vts + d1 * 128 + ((ks * 64 + l4 * 16) ^ ((d1 & 7) << 4)));
    oacc0 = mfma16(bv0, pa, oacc0);
    oacc1 = mfma16(bv1, pa, oacc1);
  }
  // out[d][t]: packed 8-B stores
  const long obase = ((long)(b * 64 + rowp)) * 1024 + h * 64 + l4 * 4;
  {
    s16x4 o0, o1;
    #pragma unroll
    for (int j = 0; j < 4; j++) { o0[j] = f2bf(oacc0[j]); o1[j] = f2bf(oacc1[j]); }
    *(s16x4*)(aout + obase + (mb + 0) * 16) = o0;
    *(s16x4*)(aout + obase + (mb + 1) * 16) = o1;
  }
}

extern "C" void kernel_launch(void* const* d_in, const int* in_sizes, int n_in,
                              void* d_out, int out_size, void* d_ws, size_t ws_size,
                              hipStream_t stream) {
  const float* x     = (const float*)d_in[0];
  const float* Wq_w  = (const float*)d_in[1];
  const float* Wq_b  = (const float*)d_in[2];
  const float* Wk_w  = (const float*)d_in[3];
  const float* Wk_b  = (const float*)d_in[4];
  const float* Wv_w  = (const float*)d_in[5];
  const float* Wv_b  = (const float*)d_in[6];
  const float* Wo_w  = (const float*)d_in[7];
  const float* Wo_b  = (const float*)d_in[8];
  const float* rel_q = (const float*)d_in[9];
  const float* rel_k = (const float*)d_in[10];
  const float* rel_v = (const float*)d_in[11];
  const int* rel_index = (const int*)d_in[12];
  float* out = (float*)d_out;

  char* ws = (char*)d_ws;
  short* x_bf   = (short*)(ws);                   // 134,217,728 (reused as aout)
  short* qkv_bf = (short*)(ws + 134217728L);      // 402,653,184
  short* wq_bf  = (short*)(ws + 536870912L);      // wq|wk|wv contiguous
  short* wo_bf  = (short*)(ws + 543162368L);
  float* biascat= (float*)(ws + 545259520L);
  short* relqb  = (short*)(ws + 545271808L);
  short* relkb  = (short*)(ws + 545763328L);
  short* relvT  = (short*)(ws + 546254848L);
  float* Dh     = (float*)(ws + 546779136L);
  short* aout   = x_bf;

  cvt_bf16_kernel<<<65536, 256, 0, stream>>>(x, x_bf, 67108864L);
  cvt_bf16_kernel<<<1024, 256, 0, stream>>>(Wq_w, wq_bf, 1048576L);
  cvt_bf16_kernel<<<1024, 256, 0, stream>>>(Wk_w, (short*)(ws + 538968064L), 1048576L);
  cvt_bf16_kernel<<<1024, 256, 0, stream>>>(Wv_w, (short*)(ws + 541065216L), 1048576L);
  cvt_bf16_kernel<<<1024, 256, 0, stream>>>(Wo_w, wo_bf, 1048576L);
  bias_cat_kernel<<<12, 256, 0, stream>>>(Wq_b, Wk_b, Wv_b, biascat);
  prep_rel_kernel<<<3840, 64, 0, stream>>>(rel_q, rel_k, rel_v, relqb, relkb, relvT, Dh);

  gemm256_kernel<1><<<3072, 512, 0, stream>>>(x_bf, wq_bf, biascat, (void*)qkv_bf,
                                              3072, 1024, 1024);
  attn_kernel<<<16384, 512, 0, stream>>>(qkv_bf, relqb, relkb, Dh, relvT, rel_index, aout);
  gemm256_kernel<0><<<1024, 512, 0, stream>>>(aout, wo_bf, Wo_b, (void*)out,
                                              1024, 1024, 1024);
}